// Round 9
// baseline (297.603 us; speedup 1.0000x reference)
//
#include <hip/hip_runtime.h>
#include <stdint.h>

#define LL 512
#define DD 64

typedef __attribute__((ext_vector_type(8))) short bf16x8;
typedef __attribute__((ext_vector_type(4))) float f32x4;

#define MFMA16(a, b, c) __builtin_amdgcn_mfma_f32_16x16x32_bf16((a), (b), (c), 0, 0, 0)

__device__ __forceinline__ float bf2f(unsigned short u) {
    union { unsigned int i; float f; } v; v.i = ((unsigned int)u) << 16; return v.f;
}
__device__ __forceinline__ unsigned short f2bf(float f) {
    union { float f; unsigned int i; } v; v.f = f;
    unsigned int i = v.i;
    return (unsigned short)((i + 0x7FFFu + ((i >> 16) & 1u)) >> 16);  // RNE
}
// Newton-refined rcp sigmoid: validated (absmax identical to exact division).
// Raw rcpf without refinement is banned (round-3 regression).
__device__ __forceinline__ float sigm(float x) {
    float d = 1.0f + __expf(-x);
    float y = __builtin_amdgcn_rcpf(d);
    return y * __builtin_fmaf(-d, y, 2.0f);
}

// ---------------------------------------------------------------- prep ------
__global__ void prep_w(const float* __restrict__ Wl, const float* __restrict__ Wr,
                       const float* __restrict__ Wlg, const float* __restrict__ Wrg,
                       const float* __restrict__ Wog, const float* __restrict__ Wout,
                       unsigned short* __restrict__ Wcat, unsigned short* __restrict__ WoutB) {
    int t = threadIdx.x + blockIdx.x * blockDim.x;
    int stride = blockDim.x * gridDim.x;
    for (int idx = t; idx < 320 * 64; idx += stride) {
        int row = idx >> 6, col = idx & 63;
        int sec = row >> 6, r = row & 63;
        float v;
        switch (sec) {
            case 0:  v = Wl[r * 64 + col];  break;
            case 1:  v = Wlg[r * 64 + col]; break;
            case 2:  v = Wr[r * 64 + col];  break;
            case 3:  v = Wrg[r * 64 + col]; break;
            default: v = Wog[r * 64 + col]; break;
        }
        Wcat[idx] = f2bf(v);
    }
    for (int idx = t; idx < 64 * 64; idx += stride) WoutB[idx] = f2bf(Wout[idx]);
}

// ------------------------------------------------- k1: LN + proj + gates ----
// (unchanged from round 6 -- validated)
__launch_bounds__(256)
__global__ void k1_proj(const float* __restrict__ pair, const float* __restrict__ torsion,
                        const float* __restrict__ ln_g, const float* __restrict__ ln_b,
                        const float* __restrict__ blg, const float* __restrict__ brg,
                        const float* __restrict__ bog, const float* __restrict__ Wt,
                        const float* __restrict__ bt, const unsigned short* __restrict__ Wcat,
                        unsigned short* __restrict__ At, unsigned short* __restrict__ Bt,
                        unsigned short* __restrict__ G) {
    const int bb = blockIdx.z, irow = blockIdx.y, c0 = blockIdx.x * 128;
    const int t = threadIdx.x, w = t >> 6, lane = t & 63;
    const int rsel = lane & 15, koff = lane >> 4;
    const int col = w * 16 + rsel;            // this wave's output channel
    __shared__ unsigned short zs[128][72];    // z bf16 [pos][d]; later reused for G
    __shared__ unsigned short awL[64][132];   // aw d-major [d][pos]
    __shared__ unsigned short bL[64][132];    // b  d-major [d][pos]

    float tww;
    {
        float acc = bt[0];
        #pragma unroll
        for (int n = 0; n < 6; ++n) acc += torsion[(bb * LL + irow) * 6 + n] * Wt[n];
        tww = sigm(acc);
    }

    // Hoisted weight fragments: 5 matrices x 2 k-halves, 16B each (40 VGPR).
    bf16x8 wfr[5][2];
    #pragma unroll
    for (int s = 0; s < 5; ++s)
        #pragma unroll
        for (int kh = 0; kh < 2; ++kh)
            wfr[s][kh] = *(const bf16x8*)&Wcat[(size_t)(s * 64 + col) * 64 + kh * 32 + koff * 8];
    const float vblg = blg[col], vbrg = brg[col], vbog = bog[col];

    // ---- LN: 4 lanes per row, 16 elems/lane in registers, 2 shuffle levels --
    {
        const int sub = lane & 3, rr = lane >> 2;
        const float4* pr4 = (const float4*)(pair + ((size_t)(bb * LL + irow) * LL + c0) * DD);
        #pragma unroll
        for (int p = 0; p < 2; ++p) {
            const int row = w * 32 + p * 16 + rr;
            float4 x[4];
            #pragma unroll
            for (int q = 0; q < 4; ++q) x[q] = pr4[row * 16 + sub * 4 + q];
            float s = 0.f, s2 = 0.f;
            #pragma unroll
            for (int q = 0; q < 4; ++q) {
                s += x[q].x + x[q].y + x[q].z + x[q].w;
                s2 += x[q].x * x[q].x + x[q].y * x[q].y + x[q].z * x[q].z + x[q].w * x[q].w;
            }
            s += __shfl_xor(s, 1);  s2 += __shfl_xor(s2, 1);
            s += __shfl_xor(s, 2);  s2 += __shfl_xor(s2, 2);
            float m = s * 0.015625f;
            float var = s2 * 0.015625f - m * m;
            float rstd = rsqrtf(var + 1e-5f);
            #pragma unroll
            for (int q = 0; q < 4; ++q) {
                float4 lg4 = ((const float4*)ln_g)[sub * 4 + q];
                float4 lb4 = ((const float4*)ln_b)[sub * 4 + q];
                ushort4 zw;
                zw.x = f2bf((x[q].x - m) * rstd * lg4.x + lb4.x);
                zw.y = f2bf((x[q].y - m) * rstd * lg4.y + lb4.y);
                zw.z = f2bf((x[q].z - m) * rstd * lg4.z + lb4.z);
                zw.w = f2bf((x[q].w - m) * rstd * lg4.w + lb4.w);
                *(ushort4*)&zs[row][sub * 16 + q * 4] = zw;
            }
        }
    }
    __syncthreads();

    // ---- projections: 8 position tiles, weights stay in registers ----
    ushort4 gk[8];
    #pragma unroll
    for (int mi = 0; mi < 8; ++mi) {
        bf16x8 a0 = *(const bf16x8*)&zs[mi * 16 + rsel][koff * 8];
        bf16x8 a1 = *(const bf16x8*)&zs[mi * 16 + rsel][32 + koff * 8];
        f32x4 pl = {0.f, 0.f, 0.f, 0.f}, plg = pl, pr = pl, prg = pl, pog = pl;
        pl  = MFMA16(a0, wfr[0][0], pl);  pl  = MFMA16(a1, wfr[0][1], pl);
        plg = MFMA16(a0, wfr[1][0], plg); plg = MFMA16(a1, wfr[1][1], plg);
        pr  = MFMA16(a0, wfr[2][0], pr);  pr  = MFMA16(a1, wfr[2][1], pr);
        prg = MFMA16(a0, wfr[3][0], prg); prg = MFMA16(a1, wfr[3][1], prg);
        pog = MFMA16(a0, wfr[4][0], pog); pog = MFMA16(a1, wfr[4][1], pog);

        const int crow = mi * 16 + koff * 4;
        unsigned short aw4[4], bm4[4], g4[4];
        #pragma unroll
        for (int r = 0; r < 4; ++r) {
            float av = pl[r] * sigm(plg[r] + vblg) * tww;
            float bv = pr[r] * sigm(prg[r] + vbrg);
            float gv = sigm(pog[r] + vbog);
            aw4[r] = f2bf(av); bm4[r] = f2bf(bv); g4[r] = f2bf(gv);
        }
        *(ushort4*)&awL[col][crow] = make_ushort4(aw4[0], aw4[1], aw4[2], aw4[3]);
        *(ushort4*)&bL[col][crow]  = make_ushort4(bm4[0], bm4[1], bm4[2], bm4[3]);
        gk[mi] = make_ushort4(g4[0], g4[1], g4[2], g4[3]);
    }
    __syncthreads();   // all waves done reading z from zs

    // Dump gate regs into zs (wave-private cells), [pos][d] == G layout.
    #pragma unroll
    for (int mi = 0; mi < 8; ++mi) {
        const int rbase = mi * 16 + koff * 4;
        zs[rbase + 0][col] = gk[mi].x;
        zs[rbase + 1][col] = gk[mi].y;
        zs[rbase + 2][col] = gk[mi].z;
        zs[rbase + 3][col] = gk[mi].w;
    }
    __syncthreads();

    // Tail: all global stores fire-and-forget (no barrier after this point).
    #pragma unroll
    for (int it = 0; it < 8; ++it) {
        int d = it * 8 + (t >> 5);
        int c8 = (t & 31) * 4;
        size_t base = ((size_t)(bb * 64 + d) * LL + irow) * LL + c0 + c8;
        *(ushort4*)&At[base] = *(const ushort4*)&awL[d][c8];
        *(ushort4*)&Bt[base] = *(const ushort4*)&bL[d][c8];
    }
    #pragma unroll
    for (int it = 0; it < 8; ++it) {
        int r = it * 16 + (t >> 4), cc = (t & 15) * 4;
        size_t pos = (size_t)(bb * LL + irow) * LL + c0 + r;
        *(ushort4*)&G[pos * DD + cc] = *(const ushort4*)&zs[r][cc];
    }
}

// ------------------------------------------ k2: batched plane GEMM (AB^T) ---
// Round-9: barrier-free. Any LDS-staged schedule pays a vmcnt(0) drain +
// barrier per 16 MFMAs (r7/r8 both ~94us, ~95% stall). The MFMA fragment
// pattern (lane=koff*16+rsel -> row base+rsel, 16B at k0+koff*8) is directly
// loadable from global, so each wave owns an independent 64x64 quadrant,
// loads its 8 fragments/K-step straight into VGPRs, zero LDS ops and zero
// barriers in the main loop. Waves slip freely; compiler pipelines loads
// with counted vmcnt. Epilogue: conflict-free LDS transpose, one barrier.
// Same fragments, same MFMA order as r6-r8 -> numerics unchanged.
__launch_bounds__(256, 2)
__global__ void k2_gemm(const unsigned short* __restrict__ At,
                        const unsigned short* __restrict__ Bt,
                        unsigned short* __restrict__ Xt) {
    int lin = blockIdx.x + (blockIdx.y << 4);          // 2048 blocks
    int nlin = (lin & 7) * 256 + (lin >> 3);           // bijective XCD chunking
    const int p = nlin >> 4;
    const int tile = nlin & 15;
    const int i0 = (tile >> 2) * 128, j0 = (tile & 3) * 128;
    const int t = threadIdx.x, lane = t & 63, w = t >> 6;
    const int wm = w >> 1, wn = w & 1;
    const int rsel = lane & 15, koff = lane >> 4;
    __shared__ unsigned short Cs[128][136];            // epilogue staging only

    f32x4 acc[4][4];
    #pragma unroll
    for (int i = 0; i < 4; ++i)
        #pragma unroll
        for (int j = 0; j < 4; ++j) acc[i][j] = (f32x4){0.f, 0.f, 0.f, 0.f};

    // Per-lane fragment base: row = i0 + wm*64 + mi*16 + rsel, 16B at koff*8.
    const unsigned short* ap =
        At + (size_t)p * LL * LL + (size_t)(i0 + wm * 64 + rsel) * LL + koff * 8;
    const unsigned short* bp =
        Bt + (size_t)p * LL * LL + (size_t)(j0 + wn * 64 + rsel) * LL + koff * 8;

    for (int k0 = 0; k0 < LL; k0 += 32) {
        bf16x8 af[4], bfr[4];
        #pragma unroll
        for (int mi = 0; mi < 4; ++mi)
            af[mi] = *(const bf16x8*)(ap + (size_t)mi * 16 * LL + k0);
        #pragma unroll
        for (int ni = 0; ni < 4; ++ni)
            bfr[ni] = *(const bf16x8*)(bp + (size_t)ni * 16 * LL + k0);
        #pragma unroll
        for (int mi = 0; mi < 4; ++mi)
            #pragma unroll
            for (int ni = 0; ni < 4; ++ni)
                acc[mi][ni] = MFMA16(af[mi], bfr[ni], acc[mi][ni]);
    }

    // Epilogue: stage C through LDS (waves write disjoint quadrants).
    const float s = 1.0f / (sqrtf((float)LL) + 1e-8f);
    #pragma unroll
    for (int mi = 0; mi < 4; ++mi)
        #pragma unroll
        for (int ni = 0; ni < 4; ++ni)
            #pragma unroll
            for (int r = 0; r < 4; ++r)
                Cs[wm * 64 + mi * 16 + koff * 4 + r][wn * 64 + ni * 16 + rsel] =
                    f2bf(acc[mi][ni][r] * s);
    __syncthreads();
    #pragma unroll
    for (int it = 0; it < 8; ++it) {
        int row = it * 16 + (t >> 4), colc = (t & 15) * 8;
        uint4 v = *(const uint4*)&Cs[row][colc];
        *(uint4*)&Xt[((size_t)p * LL + i0 + row) * LL + j0 + colc] = v;
    }
}

// ----------------------------- k3: transpose + LN + out-proj + gate + res ---
// (unchanged from round 6)
__launch_bounds__(256)
__global__ void k3_out(const unsigned short* __restrict__ Xt, const unsigned short* __restrict__ G,
                       const float* __restrict__ pairIn, const unsigned short* __restrict__ WoutB,
                       const float* __restrict__ lno_g, const float* __restrict__ lno_b,
                       const float* __restrict__ bout, float* __restrict__ out) {
    const int bb = blockIdx.z, irow = blockIdx.y, c0 = blockIdx.x * 128;
    const int t = threadIdx.x, w = t >> 6, lane = t & 63;
    __shared__ unsigned short x1[64][128];   // [d][c] staging, reused as o_lds [128][64]
    __shared__ unsigned short x2[128][72];   // [c][d] transposed

    #pragma unroll
    for (int q = 0; q < 4; ++q) {
        int idx = t + q * 256, d = idx >> 4, c8 = idx & 15;
        uint4 v = *(const uint4*)&Xt[((size_t)(bb * 64 + d) * LL + irow) * LL + c0 + c8 * 8];
        *(uint4*)&x1[d][c8 * 8] = v;
    }
    __syncthreads();
    {
        const int c = t & 127, half = t >> 7;
        unsigned short tmp[32];
        #pragma unroll
        for (int dd = 0; dd < 32; ++dd) tmp[dd] = x1[half * 32 + dd][c];
        #pragma unroll
        for (int q = 0; q < 4; ++q)
            *(uint4*)&x2[c][half * 32 + q * 8] = *(const uint4*)&tmp[q * 8];
    }
    __syncthreads();

    // ---- LN: 4 lanes per row, 16 elems/lane, 2 shuffle levels ----
    {
        const int sub = lane & 3, rr = lane >> 2;
        #pragma unroll
        for (int p = 0; p < 2; ++p) {
            const int row = w * 32 + p * 16 + rr;
            ushort4 raw[4];
            #pragma unroll
            for (int q = 0; q < 4; ++q) raw[q] = *(const ushort4*)&x2[row][sub * 16 + q * 4];
            float xv[16];
            #pragma unroll
            for (int q = 0; q < 4; ++q) {
                xv[q * 4 + 0] = bf2f(raw[q].x);
                xv[q * 4 + 1] = bf2f(raw[q].y);
                xv[q * 4 + 2] = bf2f(raw[q].z);
                xv[q * 4 + 3] = bf2f(raw[q].w);
            }
            float s = 0.f, s2 = 0.f;
            #pragma unroll
            for (int e = 0; e < 16; ++e) { s += xv[e]; s2 += xv[e] * xv[e]; }
            s += __shfl_xor(s, 1);  s2 += __shfl_xor(s2, 1);
            s += __shfl_xor(s, 2);  s2 += __shfl_xor(s2, 2);
            float m = s * 0.015625f;
            float var = s2 * 0.015625f - m * m;
            float rstd = rsqrtf(var + 1e-5f);
            #pragma unroll
            for (int q = 0; q < 4; ++q) {
                float4 lg4 = ((const float4*)lno_g)[sub * 4 + q];
                float4 lb4 = ((const float4*)lno_b)[sub * 4 + q];
                ushort4 zw;
                zw.x = f2bf((xv[q * 4 + 0] - m) * rstd * lg4.x + lb4.x);
                zw.y = f2bf((xv[q * 4 + 1] - m) * rstd * lg4.y + lb4.y);
                zw.z = f2bf((xv[q * 4 + 2] - m) * rstd * lg4.z + lb4.z);
                zw.w = f2bf((xv[q * 4 + 3] - m) * rstd * lg4.w + lb4.w);
                *(ushort4*)&x2[row][sub * 16 + q * 4] = zw;
            }
        }
    }
    __syncthreads();

    unsigned short* o_lds = &x1[0][0];   // [128][64]
    const int rsel = lane & 15, koff = lane >> 4;
    #pragma unroll
    for (int mh = 0; mh < 2; ++mh) {
        const int mi = 2 * w + mh;
        bf16x8 a0 = *(const bf16x8*)&x2[mi * 16 + rsel][koff * 8];
        bf16x8 a1 = *(const bf16x8*)&x2[mi * 16 + rsel][32 + koff * 8];
        #pragma unroll
        for (int n = 0; n < 4; ++n) {
            f32x4 pacc = {0.f, 0.f, 0.f, 0.f};
            const unsigned short* wrow = WoutB + (size_t)(n * 16 + rsel) * 64;
            pacc = MFMA16(a0, *(const bf16x8*)&wrow[koff * 8], pacc);
            pacc = MFMA16(a1, *(const bf16x8*)&wrow[32 + koff * 8], pacc);
            const float bo = bout[n * 16 + rsel];
            #pragma unroll
            for (int r = 0; r < 4; ++r)
                o_lds[(mi * 16 + koff * 4 + r) * 64 + n * 16 + rsel] = f2bf(pacc[r] + bo);
        }
    }
    __syncthreads();

    #pragma unroll
    for (int q = 0; q < 4; ++q) {
        int e = q * 2048 + t * 8;
        int c = e >> 6, o = e & 63;
        size_t pos = (size_t)(bb * LL + irow) * LL + c0 + c;
        uint4 ov = *(const uint4*)&o_lds[c * 64 + o];
        uint4 gv = *(const uint4*)&G[pos * DD + o];
        const unsigned short* ovp = (const unsigned short*)&ov;
        const unsigned short* gvp = (const unsigned short*)&gv;
        float4 p0 = *(const float4*)&pairIn[pos * DD + o];
        float4 p1 = *(const float4*)&pairIn[pos * DD + o + 4];
        float4 r0, r1;
        r0.x = p0.x + bf2f(ovp[0]) * bf2f(gvp[0]);
        r0.y = p0.y + bf2f(ovp[1]) * bf2f(gvp[1]);
        r0.z = p0.z + bf2f(ovp[2]) * bf2f(gvp[2]);
        r0.w = p0.w + bf2f(ovp[3]) * bf2f(gvp[3]);
        r1.x = p1.x + bf2f(ovp[4]) * bf2f(gvp[4]);
        r1.y = p1.y + bf2f(ovp[5]) * bf2f(gvp[5]);
        r1.z = p1.z + bf2f(ovp[6]) * bf2f(gvp[6]);
        r1.w = p1.w + bf2f(ovp[7]) * bf2f(gvp[7]);
        *(float4*)&out[pos * DD + o] = r0;
        *(float4*)&out[pos * DD + o + 4] = r1;
    }
}

// ----------------------------------------------------------------- launch ---
extern "C" void kernel_launch(void* const* d_in, const int* in_sizes, int n_in,
                              void* d_out, int out_size, void* d_ws, size_t ws_size,
                              hipStream_t stream) {
    const float* pair    = (const float*)d_in[0];
    const float* torsion = (const float*)d_in[1];
    const float* ln_g    = (const float*)d_in[2];
    const float* ln_b    = (const float*)d_in[3];
    const float* Wl      = (const float*)d_in[4];
    const float* Wr      = (const float*)d_in[5];
    const float* Wlg     = (const float*)d_in[6];
    const float* blg     = (const float*)d_in[7];
    const float* Wrg     = (const float*)d_in[8];
    const float* brg     = (const float*)d_in[9];
    const float* Wog     = (const float*)d_in[10];
    const float* bog     = (const float*)d_in[11];
    const float* Wout    = (const float*)d_in[12];
    const float* bout    = (const float*)d_in[13];
    const float* lno_g   = (const float*)d_in[14];
    const float* lno_b   = (const float*)d_in[15];
    const float* Wt      = (const float*)d_in[16];
    const float* bt      = (const float*)d_in[17];
    float* outp = (float*)d_out;

    const size_t PLANE_B = (size_t)128 * LL * LL * 2;   // 64 MiB per block
    const size_t need = 4 * PLANE_B + (320 * 64 + 64 * 64) * 2;
    if (ws_size < need) return;

    char* ws = (char*)d_ws;
    unsigned short* At    = (unsigned short*)(ws);
    unsigned short* Bt_   = (unsigned short*)(ws + PLANE_B);
    unsigned short* G     = (unsigned short*)(ws + 2 * PLANE_B);
    unsigned short* Xt    = (unsigned short*)(ws + 3 * PLANE_B);
    unsigned short* Wcat  = (unsigned short*)(ws + 4 * PLANE_B);
    unsigned short* WoutB = Wcat + 320 * 64;

    prep_w<<<dim3(40), dim3(256), 0, stream>>>(Wl, Wr, Wlg, Wrg, Wog, Wout, Wcat, WoutB);
    k1_proj<<<dim3(4, LL, 2), dim3(256), 0, stream>>>(pair, torsion, ln_g, ln_b, blg, brg,
                                                      bog, Wt, bt, Wcat, At, Bt_, G);
    k2_gemm<<<dim3(16, 128), dim3(256), 0, stream>>>(At, Bt_, Xt);
    k3_out<<<dim3(4, LL, 2), dim3(256), 0, stream>>>(Xt, G, pair, WoutB, lno_g, lno_b, bout, outp);
}

// Round 10
// 260.579 us; speedup vs baseline: 1.1421x; 1.1421x over previous
//
#include <hip/hip_runtime.h>
#include <stdint.h>

#define LL 512
#define DD 64

typedef __attribute__((ext_vector_type(8))) short bf16x8;
typedef __attribute__((ext_vector_type(4))) float f32x4;

#define MFMA16(a, b, c) __builtin_amdgcn_mfma_f32_16x16x32_bf16((a), (b), (c), 0, 0, 0)

__device__ __forceinline__ float bf2f(unsigned short u) {
    union { unsigned int i; float f; } v; v.i = ((unsigned int)u) << 16; return v.f;
}
__device__ __forceinline__ unsigned short f2bf(float f) {
    union { float f; unsigned int i; } v; v.f = f;
    unsigned int i = v.i;
    return (unsigned short)((i + 0x7FFFu + ((i >> 16) & 1u)) >> 16);  // RNE
}
// Newton-refined rcp sigmoid: validated. Raw rcpf banned (round-3 regression).
__device__ __forceinline__ float sigm(float x) {
    float d = 1.0f + __expf(-x);
    float y = __builtin_amdgcn_rcpf(d);
    return y * __builtin_fmaf(-d, y, 2.0f);
}

// ---------------------------------------------------------------- prep ------
__global__ void prep_w(const float* __restrict__ Wl, const float* __restrict__ Wr,
                       const float* __restrict__ Wlg, const float* __restrict__ Wrg,
                       const float* __restrict__ Wog, const float* __restrict__ Wout,
                       unsigned short* __restrict__ Wcat, unsigned short* __restrict__ WoutB) {
    int t = threadIdx.x + blockIdx.x * blockDim.x;
    int stride = blockDim.x * gridDim.x;
    for (int idx = t; idx < 320 * 64; idx += stride) {
        int row = idx >> 6, col = idx & 63;
        int sec = row >> 6, r = row & 63;
        float v;
        switch (sec) {
            case 0:  v = Wl[r * 64 + col];  break;
            case 1:  v = Wlg[r * 64 + col]; break;
            case 2:  v = Wr[r * 64 + col];  break;
            case 3:  v = Wrg[r * 64 + col]; break;
            default: v = Wog[r * 64 + col]; break;
        }
        Wcat[idx] = f2bf(v);
    }
    for (int idx = t; idx < 64 * 64; idx += stride) WoutB[idx] = f2bf(Wout[idx]);
}

// ------------------------------------------------- k1: LN + proj + gates ----
// Round-10: block covers 4 irows x 32 j (same 128 positions) so At2/Bt2
// fragment-tiled stores are full-64B-line dense. At2 layout (shorts):
//   [((p*4+it)*16 + k)*4096 + wm*2048 + mi*512 + lane*8 + e]
// holding A[i = it*128+wm*64+mi*16+(lane&15)][kk = k*32+(lane>>4)*8+e].
// Verified: i-decomposition == 4a+il, kk == c0j+jl (round-10 notes).
__launch_bounds__(256)
__global__ void k1_proj(const float* __restrict__ pair, const float* __restrict__ torsion,
                        const float* __restrict__ ln_g, const float* __restrict__ ln_b,
                        const float* __restrict__ blg, const float* __restrict__ brg,
                        const float* __restrict__ bog, const float* __restrict__ Wt,
                        const float* __restrict__ bt, const unsigned short* __restrict__ Wcat,
                        unsigned short* __restrict__ At2, unsigned short* __restrict__ Bt2,
                        unsigned short* __restrict__ G) {
    const int cj = blockIdx.x;           // j-chunk of 32 (k-block index)
    const int a  = blockIdx.y;           // irow group: rows 4a..4a+3
    const int bb = blockIdx.z;
    const int c0j = cj * 32;
    const int t = threadIdx.x, w = t >> 6, lane = t & 63;
    const int rsel = lane & 15, koff = lane >> 4;
    const int col = w * 16 + rsel;            // this wave's output channel
    __shared__ unsigned short zs[128][72];    // z bf16 [pos][d]; later reused for G
    __shared__ unsigned short awL[64][136];   // aw d-major [d][pos], pitch 272B (16B-aligned)
    __shared__ unsigned short bL[64][136];    // b  d-major [d][pos]

    // Torsion gate per local irow (il = pos>>5).
    float tw4[4];
    #pragma unroll
    for (int il = 0; il < 4; ++il) {
        float acc = bt[0];
        #pragma unroll
        for (int n = 0; n < 6; ++n)
            acc += torsion[((size_t)(bb * LL + 4 * a + il)) * 6 + n] * Wt[n];
        tw4[il] = sigm(acc);
    }

    // Hoisted weight fragments: 5 matrices x 2 k-halves, 16B each (40 VGPR).
    bf16x8 wfr[5][2];
    #pragma unroll
    for (int s = 0; s < 5; ++s)
        #pragma unroll
        for (int kh = 0; kh < 2; ++kh)
            wfr[s][kh] = *(const bf16x8*)&Wcat[(size_t)(s * 64 + col) * 64 + kh * 32 + koff * 8];
    const float vblg = blg[col], vbrg = brg[col], vbog = bog[col];

    // ---- LN: 4 lanes per row, 16 elems/lane, 2 shuffle levels.
    // Wave w handles pos w*32..w*32+31  ->  il = w (contiguous pair block).
    {
        const int sub = lane & 3, rr = lane >> 2;
        const float4* pr4 = (const float4*)(pair +
            (((size_t)(bb * LL + 4 * a + w) * LL) + c0j) * DD);
        #pragma unroll
        for (int p = 0; p < 2; ++p) {
            const int rl = p * 16 + rr;          // local row in wave's 32
            float4 x[4];
            #pragma unroll
            for (int q = 0; q < 4; ++q) x[q] = pr4[rl * 16 + sub * 4 + q];
            float s = 0.f, s2 = 0.f;
            #pragma unroll
            for (int q = 0; q < 4; ++q) {
                s += x[q].x + x[q].y + x[q].z + x[q].w;
                s2 += x[q].x * x[q].x + x[q].y * x[q].y + x[q].z * x[q].z + x[q].w * x[q].w;
            }
            s += __shfl_xor(s, 1);  s2 += __shfl_xor(s2, 1);
            s += __shfl_xor(s, 2);  s2 += __shfl_xor(s2, 2);
            float m = s * 0.015625f;
            float var = s2 * 0.015625f - m * m;
            float rstd = rsqrtf(var + 1e-5f);
            #pragma unroll
            for (int q = 0; q < 4; ++q) {
                float4 lg4 = ((const float4*)ln_g)[sub * 4 + q];
                float4 lb4 = ((const float4*)ln_b)[sub * 4 + q];
                ushort4 zw;
                zw.x = f2bf((x[q].x - m) * rstd * lg4.x + lb4.x);
                zw.y = f2bf((x[q].y - m) * rstd * lg4.y + lb4.y);
                zw.z = f2bf((x[q].z - m) * rstd * lg4.z + lb4.z);
                zw.w = f2bf((x[q].w - m) * rstd * lg4.w + lb4.w);
                *(ushort4*)&zs[w * 32 + rl][sub * 16 + q * 4] = zw;
            }
        }
    }
    __syncthreads();

    // ---- projections: 8 position tiles, weights stay in registers ----
    ushort4 gk[8];
    #pragma unroll
    for (int mi = 0; mi < 8; ++mi) {
        bf16x8 a0 = *(const bf16x8*)&zs[mi * 16 + rsel][koff * 8];
        bf16x8 a1 = *(const bf16x8*)&zs[mi * 16 + rsel][32 + koff * 8];
        f32x4 pl = {0.f, 0.f, 0.f, 0.f}, plg = pl, pr = pl, prg = pl, pog = pl;
        pl  = MFMA16(a0, wfr[0][0], pl);  pl  = MFMA16(a1, wfr[0][1], pl);
        plg = MFMA16(a0, wfr[1][0], plg); plg = MFMA16(a1, wfr[1][1], plg);
        pr  = MFMA16(a0, wfr[2][0], pr);  pr  = MFMA16(a1, wfr[2][1], pr);
        prg = MFMA16(a0, wfr[3][0], prg); prg = MFMA16(a1, wfr[3][1], prg);
        pog = MFMA16(a0, wfr[4][0], pog); pog = MFMA16(a1, wfr[4][1], pog);

        const float tww = tw4[mi >> 1];       // il = pos>>5 = mi>>1
        const int crow = mi * 16 + koff * 4;
        unsigned short aw4[4], bm4[4], g4[4];
        #pragma unroll
        for (int r = 0; r < 4; ++r) {
            float av = pl[r] * sigm(plg[r] + vblg) * tww;
            float bv = pr[r] * sigm(prg[r] + vbrg);
            float gv = sigm(pog[r] + vbog);
            aw4[r] = f2bf(av); bm4[r] = f2bf(bv); g4[r] = f2bf(gv);
        }
        *(ushort4*)&awL[col][crow] = make_ushort4(aw4[0], aw4[1], aw4[2], aw4[3]);
        *(ushort4*)&bL[col][crow]  = make_ushort4(bm4[0], bm4[1], bm4[2], bm4[3]);
        gk[mi] = make_ushort4(g4[0], g4[1], g4[2], g4[3]);
    }
    __syncthreads();   // all waves done reading z from zs

    // Dump gate regs into zs (wave-private cells), [pos][d] == G layout.
    #pragma unroll
    for (int mi = 0; mi < 8; ++mi) {
        const int rbase = mi * 16 + koff * 4;
        zs[rbase + 0][col] = gk[mi].x;
        zs[rbase + 1][col] = gk[mi].y;
        zs[rbase + 2][col] = gk[mi].z;
        zs[rbase + 3][col] = gk[mi].w;
    }
    __syncthreads();

    // ---- At2/Bt2 writeout: fragment-tiled, full-64B-line dense ----
    // thread t, iter q: chunk = (d = q*16 + t>>4, g = (t>>2)&3, il = t&3)
    // 4 il lanes cover one 64B line completely; fire-and-forget stores.
    const int itb = a >> 5;
    const int wmb = (a >> 4) & 1;
    const int mif = (a >> 2) & 3;
    const int ri0 = (a & 3) * 4;
    {
        const int il = t & 3, g = (t >> 2) & 3, dlow = t >> 4;
        const int lfrag = g * 16 + ri0 + il;
        #pragma unroll
        for (int q = 0; q < 4; ++q) {
            const int d = q * 16 + dlow;
            const int p = bb * 64 + d;
            size_t base = (((size_t)(p * 4 + itb) * 16 + cj) * 4096)
                        + wmb * 2048 + mif * 512 + (size_t)lfrag * 8;
            *(uint4*)&At2[base] = *(const uint4*)&awL[d][il * 32 + g * 8];
            *(uint4*)&Bt2[base] = *(const uint4*)&bL[d][il * 32 + g * 8];
        }
    }
    // G: pos -> (i = 4a + (pos>>5), j = c0j + (pos&31)); 2KB contiguous/instr.
    #pragma unroll
    for (int it8 = 0; it8 < 8; ++it8) {
        int r = it8 * 16 + (t >> 4), cc = (t & 15) * 4;
        size_t pos = ((size_t)(bb * LL + 4 * a + (r >> 5)) * LL) + c0j + (r & 31);
        *(ushort4*)&G[pos * DD + cc] = *(const ushort4*)&zs[r][cc];
    }
}

// ------------------------------------------ k2: batched plane GEMM (AB^T) ---
// Round-10: barrier-free main loop (r9) + fragment-tiled At2/Bt2 so every
// load is lane-contiguous (4KB dense per wave per fragment-group). No LDS,
// no barriers, no bank conflicts in the main loop; waves slip freely.
__launch_bounds__(256, 4)
__global__ void k2_gemm(const unsigned short* __restrict__ At2,
                        const unsigned short* __restrict__ Bt2,
                        unsigned short* __restrict__ Xt) {
    int lin = blockIdx.x + (blockIdx.y << 4);          // 2048 blocks
    int nlin = (lin & 7) * 256 + (lin >> 3);           // bijective XCD chunking
    const int p = nlin >> 4;
    const int tile = nlin & 15;
    const int it = tile >> 2, jt = tile & 3;
    const int i0 = it * 128, j0 = jt * 128;
    const int t = threadIdx.x, lane = t & 63, w = t >> 6;
    const int wm = w >> 1, wn = w & 1;
    __shared__ unsigned short Cs[128][136];            // epilogue staging only

    f32x4 acc[4][4];
    #pragma unroll
    for (int i = 0; i < 4; ++i)
        #pragma unroll
        for (int j = 0; j < 4; ++j) acc[i][j] = (f32x4){0.f, 0.f, 0.f, 0.f};

    const unsigned short* ap = At2 + ((size_t)(p * 4 + it) * 16) * 4096
                             + wm * 2048 + lane * 8;
    const unsigned short* bp = Bt2 + ((size_t)(p * 4 + jt) * 16) * 4096
                             + wn * 2048 + lane * 8;

    #pragma unroll 4
    for (int k = 0; k < 16; ++k) {
        bf16x8 af[4], bfr[4];
        #pragma unroll
        for (int mi = 0; mi < 4; ++mi)
            af[mi] = *(const bf16x8*)(ap + (size_t)k * 4096 + mi * 512);
        #pragma unroll
        for (int ni = 0; ni < 4; ++ni)
            bfr[ni] = *(const bf16x8*)(bp + (size_t)k * 4096 + ni * 512);
        #pragma unroll
        for (int mi = 0; mi < 4; ++mi)
            #pragma unroll
            for (int ni = 0; ni < 4; ++ni)
                acc[mi][ni] = MFMA16(af[mi], bfr[ni], acc[mi][ni]);
    }

    // Epilogue: stage C through LDS (waves write disjoint quadrants).
    const int rsel = lane & 15, koff = lane >> 4;
    const float s = 1.0f / (sqrtf((float)LL) + 1e-8f);
    #pragma unroll
    for (int mi = 0; mi < 4; ++mi)
        #pragma unroll
        for (int ni = 0; ni < 4; ++ni)
            #pragma unroll
            for (int r = 0; r < 4; ++r)
                Cs[wm * 64 + mi * 16 + koff * 4 + r][wn * 64 + ni * 16 + rsel] =
                    f2bf(acc[mi][ni][r] * s);
    __syncthreads();
    #pragma unroll
    for (int it8 = 0; it8 < 8; ++it8) {
        int row = it8 * 16 + (t >> 4), colc = (t & 15) * 8;
        uint4 v = *(const uint4*)&Cs[row][colc];
        *(uint4*)&Xt[((size_t)p * LL + i0 + row) * LL + j0 + colc] = v;
    }
}

// ----------------------------- k3: transpose + LN + out-proj + gate + res ---
// (unchanged from round 6)
__launch_bounds__(256)
__global__ void k3_out(const unsigned short* __restrict__ Xt, const unsigned short* __restrict__ G,
                       const float* __restrict__ pairIn, const unsigned short* __restrict__ WoutB,
                       const float* __restrict__ lno_g, const float* __restrict__ lno_b,
                       const float* __restrict__ bout, float* __restrict__ out) {
    const int bb = blockIdx.z, irow = blockIdx.y, c0 = blockIdx.x * 128;
    const int t = threadIdx.x, w = t >> 6, lane = t & 63;
    __shared__ unsigned short x1[64][128];   // [d][c] staging, reused as o_lds [128][64]
    __shared__ unsigned short x2[128][72];   // [c][d] transposed

    #pragma unroll
    for (int q = 0; q < 4; ++q) {
        int idx = t + q * 256, d = idx >> 4, c8 = idx & 15;
        uint4 v = *(const uint4*)&Xt[((size_t)(bb * 64 + d) * LL + irow) * LL + c0 + c8 * 8];
        *(uint4*)&x1[d][c8 * 8] = v;
    }
    __syncthreads();
    {
        const int c = t & 127, half = t >> 7;
        unsigned short tmp[32];
        #pragma unroll
        for (int dd = 0; dd < 32; ++dd) tmp[dd] = x1[half * 32 + dd][c];
        #pragma unroll
        for (int q = 0; q < 4; ++q)
            *(uint4*)&x2[c][half * 32 + q * 8] = *(const uint4*)&tmp[q * 8];
    }
    __syncthreads();

    // ---- LN: 4 lanes per row, 16 elems/lane, 2 shuffle levels ----
    {
        const int sub = lane & 3, rr = lane >> 2;
        #pragma unroll
        for (int p = 0; p < 2; ++p) {
            const int row = w * 32 + p * 16 + rr;
            ushort4 raw[4];
            #pragma unroll
            for (int q = 0; q < 4; ++q) raw[q] = *(const ushort4*)&x2[row][sub * 16 + q * 4];
            float xv[16];
            #pragma unroll
            for (int q = 0; q < 4; ++q) {
                xv[q * 4 + 0] = bf2f(raw[q].x);
                xv[q * 4 + 1] = bf2f(raw[q].y);
                xv[q * 4 + 2] = bf2f(raw[q].z);
                xv[q * 4 + 3] = bf2f(raw[q].w);
            }
            float s = 0.f, s2 = 0.f;
            #pragma unroll
            for (int e = 0; e < 16; ++e) { s += xv[e]; s2 += xv[e] * xv[e]; }
            s += __shfl_xor(s, 1);  s2 += __shfl_xor(s2, 1);
            s += __shfl_xor(s, 2);  s2 += __shfl_xor(s2, 2);
            float m = s * 0.015625f;
            float var = s2 * 0.015625f - m * m;
            float rstd = rsqrtf(var + 1e-5f);
            #pragma unroll
            for (int q = 0; q < 4; ++q) {
                float4 lg4 = ((const float4*)lno_g)[sub * 4 + q];
                float4 lb4 = ((const float4*)lno_b)[sub * 4 + q];
                ushort4 zw;
                zw.x = f2bf((xv[q * 4 + 0] - m) * rstd * lg4.x + lb4.x);
                zw.y = f2bf((xv[q * 4 + 1] - m) * rstd * lg4.y + lb4.y);
                zw.z = f2bf((xv[q * 4 + 2] - m) * rstd * lg4.z + lb4.z);
                zw.w = f2bf((xv[q * 4 + 3] - m) * rstd * lg4.w + lb4.w);
                *(ushort4*)&x2[row][sub * 16 + q * 4] = zw;
            }
        }
    }
    __syncthreads();

    unsigned short* o_lds = &x1[0][0];   // [128][64]
    const int rsel = lane & 15, koff = lane >> 4;
    #pragma unroll
    for (int mh = 0; mh < 2; ++mh) {
        const int mi = 2 * w + mh;
        bf16x8 a0 = *(const bf16x8*)&x2[mi * 16 + rsel][koff * 8];
        bf16x8 a1 = *(const bf16x8*)&x2[mi * 16 + rsel][32 + koff * 8];
        #pragma unroll
        for (int n = 0; n < 4; ++n) {
            f32x4 pacc = {0.f, 0.f, 0.f, 0.f};
            const unsigned short* wrow = WoutB + (size_t)(n * 16 + rsel) * 64;
            pacc = MFMA16(a0, *(const bf16x8*)&wrow[koff * 8], pacc);
            pacc = MFMA16(a1, *(const bf16x8*)&wrow[32 + koff * 8], pacc);
            const float bo = bout[n * 16 + rsel];
            #pragma unroll
            for (int r = 0; r < 4; ++r)
                o_lds[(mi * 16 + koff * 4 + r) * 64 + n * 16 + rsel] = f2bf(pacc[r] + bo);
        }
    }
    __syncthreads();

    #pragma unroll
    for (int q = 0; q < 4; ++q) {
        int e = q * 2048 + t * 8;
        int c = e >> 6, o = e & 63;
        size_t pos = (size_t)(bb * LL + irow) * LL + c0 + c;
        uint4 ov = *(const uint4*)&o_lds[c * 64 + o];
        uint4 gv = *(const uint4*)&G[pos * DD + o];
        const unsigned short* ovp = (const unsigned short*)&ov;
        const unsigned short* gvp = (const unsigned short*)&gv;
        float4 p0 = *(const float4*)&pairIn[pos * DD + o];
        float4 p1 = *(const float4*)&pairIn[pos * DD + o + 4];
        float4 r0, r1;
        r0.x = p0.x + bf2f(ovp[0]) * bf2f(gvp[0]);
        r0.y = p0.y + bf2f(ovp[1]) * bf2f(gvp[1]);
        r0.z = p0.z + bf2f(ovp[2]) * bf2f(gvp[2]);
        r0.w = p0.w + bf2f(ovp[3]) * bf2f(gvp[3]);
        r1.x = p1.x + bf2f(ovp[4]) * bf2f(gvp[4]);
        r1.y = p1.y + bf2f(ovp[5]) * bf2f(gvp[5]);
        r1.z = p1.z + bf2f(ovp[6]) * bf2f(gvp[6]);
        r1.w = p1.w + bf2f(ovp[7]) * bf2f(gvp[7]);
        *(float4*)&out[pos * DD + o] = r0;
        *(float4*)&out[pos * DD + o + 4] = r1;
    }
}

// ----------------------------------------------------------------- launch ---
extern "C" void kernel_launch(void* const* d_in, const int* in_sizes, int n_in,
                              void* d_out, int out_size, void* d_ws, size_t ws_size,
                              hipStream_t stream) {
    const float* pair    = (const float*)d_in[0];
    const float* torsion = (const float*)d_in[1];
    const float* ln_g    = (const float*)d_in[2];
    const float* ln_b    = (const float*)d_in[3];
    const float* Wl      = (const float*)d_in[4];
    const float* Wr      = (const float*)d_in[5];
    const float* Wlg     = (const float*)d_in[6];
    const float* blg     = (const float*)d_in[7];
    const float* Wrg     = (const float*)d_in[8];
    const float* brg     = (const float*)d_in[9];
    const float* Wog     = (const float*)d_in[10];
    const float* bog     = (const float*)d_in[11];
    const float* Wout    = (const float*)d_in[12];
    const float* bout    = (const float*)d_in[13];
    const float* lno_g   = (const float*)d_in[14];
    const float* lno_b   = (const float*)d_in[15];
    const float* Wt      = (const float*)d_in[16];
    const float* bt      = (const float*)d_in[17];
    float* outp = (float*)d_out;

    const size_t PLANE_B = (size_t)128 * LL * LL * 2;   // 64 MiB per block
    const size_t need = 4 * PLANE_B + (320 * 64 + 64 * 64) * 2;
    if (ws_size < need) return;

    char* ws = (char*)d_ws;
    unsigned short* At2   = (unsigned short*)(ws);
    unsigned short* Bt2   = (unsigned short*)(ws + PLANE_B);
    unsigned short* G     = (unsigned short*)(ws + 2 * PLANE_B);
    unsigned short* Xt    = (unsigned short*)(ws + 3 * PLANE_B);
    unsigned short* Wcat  = (unsigned short*)(ws + 4 * PLANE_B);
    unsigned short* WoutB = Wcat + 320 * 64;

    prep_w<<<dim3(40), dim3(256), 0, stream>>>(Wl, Wr, Wlg, Wrg, Wog, Wout, Wcat, WoutB);
    k1_proj<<<dim3(16, 128, 2), dim3(256), 0, stream>>>(pair, torsion, ln_g, ln_b, blg, brg,
                                                        bog, Wt, bt, Wcat, At2, Bt2, G);
    k2_gemm<<<dim3(16, 128), dim3(256), 0, stream>>>(At2, Bt2, Xt);
    k3_out<<<dim3(4, LL, 2), dim3(256), 0, stream>>>(Xt, G, pair, WoutB, lno_g, lno_b, bout, outp);
}

// Round 11
// 254.249 us; speedup vs baseline: 1.1705x; 1.0249x over previous
//
#include <hip/hip_runtime.h>
#include <stdint.h>

#define LL 512
#define DD 64

typedef __attribute__((ext_vector_type(8))) short bf16x8;
typedef __attribute__((ext_vector_type(4))) float f32x4;

#define MFMA16(a, b, c) __builtin_amdgcn_mfma_f32_16x16x32_bf16((a), (b), (c), 0, 0, 0)

__device__ __forceinline__ float bf2f(unsigned short u) {
    union { unsigned int i; float f; } v; v.i = ((unsigned int)u) << 16; return v.f;
}
__device__ __forceinline__ unsigned short f2bf(float f) {
    union { float f; unsigned int i; } v; v.f = f;
    unsigned int i = v.i;
    return (unsigned short)((i + 0x7FFFu + ((i >> 16) & 1u)) >> 16);  // RNE
}
// Newton-refined rcp sigmoid: validated. Raw rcpf banned (round-3 regression).
__device__ __forceinline__ float sigm(float x) {
    float d = 1.0f + __expf(-x);
    float y = __builtin_amdgcn_rcpf(d);
    return y * __builtin_fmaf(-d, y, 2.0f);
}

// ---------------------------------------------------------------- prep ------
__global__ void prep_w(const float* __restrict__ Wl, const float* __restrict__ Wr,
                       const float* __restrict__ Wlg, const float* __restrict__ Wrg,
                       const float* __restrict__ Wog, const float* __restrict__ Wout,
                       unsigned short* __restrict__ Wcat, unsigned short* __restrict__ WoutB) {
    int t = threadIdx.x + blockIdx.x * blockDim.x;
    int stride = blockDim.x * gridDim.x;
    for (int idx = t; idx < 320 * 64; idx += stride) {
        int row = idx >> 6, col = idx & 63;
        int sec = row >> 6, r = row & 63;
        float v;
        switch (sec) {
            case 0:  v = Wl[r * 64 + col];  break;
            case 1:  v = Wlg[r * 64 + col]; break;
            case 2:  v = Wr[r * 64 + col];  break;
            case 3:  v = Wrg[r * 64 + col]; break;
            default: v = Wog[r * 64 + col]; break;
        }
        Wcat[idx] = f2bf(v);
    }
    for (int idx = t; idx < 64 * 64; idx += stride) WoutB[idx] = f2bf(Wout[idx]);
}

// ------------------------------------------------- k1: LN + proj + gates ----
// Round-11: awL/bL pitch back to 132 (LDS 53248->52224, restores 3 blocks/CU;
// r10's 272B pitch also bank-aliased -> conflicts 1.3M->2.9M). Writeout reads
// two 8B LDS chunks (<=2-way conflicts = free) merged into one 16B store.
// Fragment-tiled At2/Bt2 layout unchanged from r10 (validated).
__launch_bounds__(256)
__global__ void k1_proj(const float* __restrict__ pair, const float* __restrict__ torsion,
                        const float* __restrict__ ln_g, const float* __restrict__ ln_b,
                        const float* __restrict__ blg, const float* __restrict__ brg,
                        const float* __restrict__ bog, const float* __restrict__ Wt,
                        const float* __restrict__ bt, const unsigned short* __restrict__ Wcat,
                        unsigned short* __restrict__ At2, unsigned short* __restrict__ Bt2,
                        unsigned short* __restrict__ G) {
    const int cj = blockIdx.x;           // j-chunk of 32 (k-block index)
    const int a  = blockIdx.y;           // irow group: rows 4a..4a+3
    const int bb = blockIdx.z;
    const int c0j = cj * 32;
    const int t = threadIdx.x, w = t >> 6, lane = t & 63;
    const int rsel = lane & 15, koff = lane >> 4;
    const int col = w * 16 + rsel;            // this wave's output channel
    __shared__ unsigned short zs[128][72];    // z bf16 [pos][d]; later reused for G
    __shared__ unsigned short awL[64][132];   // aw d-major [d][pos], pitch 264B
    __shared__ unsigned short bL[64][132];    // b  d-major [d][pos]

    // Torsion gate per local irow (il = pos>>5).
    float tw4[4];
    #pragma unroll
    for (int il = 0; il < 4; ++il) {
        float acc = bt[0];
        #pragma unroll
        for (int n = 0; n < 6; ++n)
            acc += torsion[((size_t)(bb * LL + 4 * a + il)) * 6 + n] * Wt[n];
        tw4[il] = sigm(acc);
    }

    // Hoisted weight fragments: 5 matrices x 2 k-halves, 16B each (40 VGPR).
    bf16x8 wfr[5][2];
    #pragma unroll
    for (int s = 0; s < 5; ++s)
        #pragma unroll
        for (int kh = 0; kh < 2; ++kh)
            wfr[s][kh] = *(const bf16x8*)&Wcat[(size_t)(s * 64 + col) * 64 + kh * 32 + koff * 8];
    const float vblg = blg[col], vbrg = brg[col], vbog = bog[col];

    // ---- LN: 4 lanes per row, 16 elems/lane, 2 shuffle levels.
    // Wave w handles pos w*32..w*32+31  ->  il = w.
    {
        const int sub = lane & 3, rr = lane >> 2;
        const float4* pr4 = (const float4*)(pair +
            (((size_t)(bb * LL + 4 * a + w) * LL) + c0j) * DD);
        #pragma unroll
        for (int p = 0; p < 2; ++p) {
            const int rl = p * 16 + rr;          // local row in wave's 32
            float4 x[4];
            #pragma unroll
            for (int q = 0; q < 4; ++q) x[q] = pr4[rl * 16 + sub * 4 + q];
            float s = 0.f, s2 = 0.f;
            #pragma unroll
            for (int q = 0; q < 4; ++q) {
                s += x[q].x + x[q].y + x[q].z + x[q].w;
                s2 += x[q].x * x[q].x + x[q].y * x[q].y + x[q].z * x[q].z + x[q].w * x[q].w;
            }
            s += __shfl_xor(s, 1);  s2 += __shfl_xor(s2, 1);
            s += __shfl_xor(s, 2);  s2 += __shfl_xor(s2, 2);
            float m = s * 0.015625f;
            float var = s2 * 0.015625f - m * m;
            float rstd = rsqrtf(var + 1e-5f);
            #pragma unroll
            for (int q = 0; q < 4; ++q) {
                float4 lg4 = ((const float4*)ln_g)[sub * 4 + q];
                float4 lb4 = ((const float4*)ln_b)[sub * 4 + q];
                ushort4 zw;
                zw.x = f2bf((x[q].x - m) * rstd * lg4.x + lb4.x);
                zw.y = f2bf((x[q].y - m) * rstd * lg4.y + lb4.y);
                zw.z = f2bf((x[q].z - m) * rstd * lg4.z + lb4.z);
                zw.w = f2bf((x[q].w - m) * rstd * lg4.w + lb4.w);
                *(ushort4*)&zs[w * 32 + rl][sub * 16 + q * 4] = zw;
            }
        }
    }
    __syncthreads();

    // ---- projections: 8 position tiles, weights stay in registers ----
    ushort4 gk[8];
    #pragma unroll
    for (int mi = 0; mi < 8; ++mi) {
        bf16x8 a0 = *(const bf16x8*)&zs[mi * 16 + rsel][koff * 8];
        bf16x8 a1 = *(const bf16x8*)&zs[mi * 16 + rsel][32 + koff * 8];
        f32x4 pl = {0.f, 0.f, 0.f, 0.f}, plg = pl, pr = pl, prg = pl, pog = pl;
        pl  = MFMA16(a0, wfr[0][0], pl);  pl  = MFMA16(a1, wfr[0][1], pl);
        plg = MFMA16(a0, wfr[1][0], plg); plg = MFMA16(a1, wfr[1][1], plg);
        pr  = MFMA16(a0, wfr[2][0], pr);  pr  = MFMA16(a1, wfr[2][1], pr);
        prg = MFMA16(a0, wfr[3][0], prg); prg = MFMA16(a1, wfr[3][1], prg);
        pog = MFMA16(a0, wfr[4][0], pog); pog = MFMA16(a1, wfr[4][1], pog);

        const float tww = tw4[mi >> 1];       // il = pos>>5 = mi>>1
        const int crow = mi * 16 + koff * 4;
        unsigned short aw4[4], bm4[4], g4[4];
        #pragma unroll
        for (int r = 0; r < 4; ++r) {
            float av = pl[r] * sigm(plg[r] + vblg) * tww;
            float bv = pr[r] * sigm(prg[r] + vbrg);
            float gv = sigm(pog[r] + vbog);
            aw4[r] = f2bf(av); bm4[r] = f2bf(bv); g4[r] = f2bf(gv);
        }
        *(ushort4*)&awL[col][crow] = make_ushort4(aw4[0], aw4[1], aw4[2], aw4[3]);
        *(ushort4*)&bL[col][crow]  = make_ushort4(bm4[0], bm4[1], bm4[2], bm4[3]);
        gk[mi] = make_ushort4(g4[0], g4[1], g4[2], g4[3]);
    }
    __syncthreads();   // all waves done reading z from zs

    // Dump gate regs into zs (wave-private cells), [pos][d] == G layout.
    #pragma unroll
    for (int mi = 0; mi < 8; ++mi) {
        const int rbase = mi * 16 + koff * 4;
        zs[rbase + 0][col] = gk[mi].x;
        zs[rbase + 1][col] = gk[mi].y;
        zs[rbase + 2][col] = gk[mi].z;
        zs[rbase + 3][col] = gk[mi].w;
    }
    __syncthreads();

    // ---- At2/Bt2 writeout: fragment-tiled, full-64B-line dense ----
    const int itb = a >> 5;
    const int wmb = (a >> 4) & 1;
    const int mif = (a >> 2) & 3;
    const int ri0 = (a & 3) * 4;
    {
        const int il = t & 3, g = (t >> 2) & 3, dlow = t >> 4;
        const int lfrag = g * 16 + ri0 + il;
        #pragma unroll
        for (int q = 0; q < 4; ++q) {
            const int d = q * 16 + dlow;
            const int p = bb * 64 + d;
            size_t base = (((size_t)(p * 4 + itb) * 16 + cj) * 4096)
                        + wmb * 2048 + mif * 512 + (size_t)lfrag * 8;
            uint2 alo = *(const uint2*)&awL[d][il * 32 + g * 8];
            uint2 ahi = *(const uint2*)&awL[d][il * 32 + g * 8 + 4];
            uint2 blo = *(const uint2*)&bL[d][il * 32 + g * 8];
            uint2 bhi = *(const uint2*)&bL[d][il * 32 + g * 8 + 4];
            *(uint4*)&At2[base] = make_uint4(alo.x, alo.y, ahi.x, ahi.y);
            *(uint4*)&Bt2[base] = make_uint4(blo.x, blo.y, bhi.x, bhi.y);
        }
    }
    // G: pos -> (i = 4a + (pos>>5), j = c0j + (pos&31)); 2KB contiguous/instr.
    #pragma unroll
    for (int it8 = 0; it8 < 8; ++it8) {
        int r = it8 * 16 + (t >> 4), cc = (t & 15) * 4;
        size_t pos = ((size_t)(bb * LL + 4 * a + (r >> 5)) * LL) + c0j + (r & 31);
        *(ushort4*)&G[pos * DD + cc] = *(const ushort4*)&zs[r][cc];
    }
}

// ------------------------------------------ k2: batched plane GEMM (AB^T) ---
// Round-11: explicit software pipeline. r7-r10 all ~91-94us because each
// K-step's loads were issued just-before-use -> every step pays a full
// load round-trip (measured ~1760cy/step == 1 L2/HBM latency). Now: named
// A/B fragment double-buffers (static indices), loads for step k+1 issued in
// program order BEFORE step k's 16 MFMAs -> natural counted vmcnt(8), never
// a drain. Accumulation order k=0..15 unchanged -> bit-identical results.
__launch_bounds__(256, 3)
__global__ void k2_gemm(const unsigned short* __restrict__ At2,
                        const unsigned short* __restrict__ Bt2,
                        unsigned short* __restrict__ Xt) {
    int lin = blockIdx.x + (blockIdx.y << 4);          // 2048 blocks
    int nlin = (lin & 7) * 256 + (lin >> 3);           // bijective XCD chunking
    const int p = nlin >> 4;
    const int tile = nlin & 15;
    const int it = tile >> 2, jt = tile & 3;
    const int i0 = it * 128, j0 = jt * 128;
    const int t = threadIdx.x, lane = t & 63, w = t >> 6;
    const int wm = w >> 1, wn = w & 1;
    __shared__ unsigned short Cs[128][136];            // epilogue staging only

    f32x4 acc[4][4];
    #pragma unroll
    for (int i = 0; i < 4; ++i)
        #pragma unroll
        for (int j = 0; j < 4; ++j) acc[i][j] = (f32x4){0.f, 0.f, 0.f, 0.f};

    const unsigned short* ap = At2 + ((size_t)(p * 4 + it) * 16) * 4096
                             + wm * 2048 + lane * 8;
    const unsigned short* bp = Bt2 + ((size_t)(p * 4 + jt) * 16) * 4096
                             + wn * 2048 + lane * 8;

    bf16x8 aA[4], bA[4], aB[4], bB[4];
    #pragma unroll
    for (int m = 0; m < 4; ++m) {
        aA[m] = *(const bf16x8*)(ap + m * 512);
        bA[m] = *(const bf16x8*)(bp + m * 512);
    }
    #pragma unroll
    for (int kk = 0; kk < 8; ++kk) {
        // prefetch step 2kk+1 into B-buffers (before A's MFMAs)
        #pragma unroll
        for (int m = 0; m < 4; ++m) {
            aB[m] = *(const bf16x8*)(ap + (size_t)(2 * kk + 1) * 4096 + m * 512);
            bB[m] = *(const bf16x8*)(bp + (size_t)(2 * kk + 1) * 4096 + m * 512);
        }
        #pragma unroll
        for (int mi = 0; mi < 4; ++mi)
            #pragma unroll
            for (int ni = 0; ni < 4; ++ni)
                acc[mi][ni] = MFMA16(aA[mi], bA[ni], acc[mi][ni]);
        if (kk < 7) {
            // prefetch step 2kk+2 into A-buffers (before B's MFMAs)
            #pragma unroll
            for (int m = 0; m < 4; ++m) {
                aA[m] = *(const bf16x8*)(ap + (size_t)(2 * kk + 2) * 4096 + m * 512);
                bA[m] = *(const bf16x8*)(bp + (size_t)(2 * kk + 2) * 4096 + m * 512);
            }
        }
        #pragma unroll
        for (int mi = 0; mi < 4; ++mi)
            #pragma unroll
            for (int ni = 0; ni < 4; ++ni)
                acc[mi][ni] = MFMA16(aB[mi], bB[ni], acc[mi][ni]);
    }

    // Epilogue: stage C through LDS (waves write disjoint quadrants).
    const int rsel = lane & 15, koff = lane >> 4;
    const float s = 1.0f / (sqrtf((float)LL) + 1e-8f);
    #pragma unroll
    for (int mi = 0; mi < 4; ++mi)
        #pragma unroll
        for (int ni = 0; ni < 4; ++ni)
            #pragma unroll
            for (int r = 0; r < 4; ++r)
                Cs[wm * 64 + mi * 16 + koff * 4 + r][wn * 64 + ni * 16 + rsel] =
                    f2bf(acc[mi][ni][r] * s);
    __syncthreads();
    #pragma unroll
    for (int it8 = 0; it8 < 8; ++it8) {
        int row = it8 * 16 + (t >> 4), colc = (t & 15) * 8;
        uint4 v = *(const uint4*)&Cs[row][colc];
        *(uint4*)&Xt[((size_t)p * LL + i0 + row) * LL + j0 + colc] = v;
    }
}

// ----------------------------- k3: transpose + LN + out-proj + gate + res ---
// (unchanged -- measured at ~94% of achievable HBM BW, at roofline)
__launch_bounds__(256)
__global__ void k3_out(const unsigned short* __restrict__ Xt, const unsigned short* __restrict__ G,
                       const float* __restrict__ pairIn, const unsigned short* __restrict__ WoutB,
                       const float* __restrict__ lno_g, const float* __restrict__ lno_b,
                       const float* __restrict__ bout, float* __restrict__ out) {
    const int bb = blockIdx.z, irow = blockIdx.y, c0 = blockIdx.x * 128;
    const int t = threadIdx.x, w = t >> 6, lane = t & 63;
    __shared__ unsigned short x1[64][128];   // [d][c] staging, reused as o_lds [128][64]
    __shared__ unsigned short x2[128][72];   // [c][d] transposed

    #pragma unroll
    for (int q = 0; q < 4; ++q) {
        int idx = t + q * 256, d = idx >> 4, c8 = idx & 15;
        uint4 v = *(const uint4*)&Xt[((size_t)(bb * 64 + d) * LL + irow) * LL + c0 + c8 * 8];
        *(uint4*)&x1[d][c8 * 8] = v;
    }
    __syncthreads();
    {
        const int c = t & 127, half = t >> 7;
        unsigned short tmp[32];
        #pragma unroll
        for (int dd = 0; dd < 32; ++dd) tmp[dd] = x1[half * 32 + dd][c];
        #pragma unroll
        for (int q = 0; q < 4; ++q)
            *(uint4*)&x2[c][half * 32 + q * 8] = *(const uint4*)&tmp[q * 8];
    }
    __syncthreads();

    // ---- LN: 4 lanes per row, 16 elems/lane, 2 shuffle levels ----
    {
        const int sub = lane & 3, rr = lane >> 2;
        #pragma unroll
        for (int p = 0; p < 2; ++p) {
            const int row = w * 32 + p * 16 + rr;
            ushort4 raw[4];
            #pragma unroll
            for (int q = 0; q < 4; ++q) raw[q] = *(const ushort4*)&x2[row][sub * 16 + q * 4];
            float xv[16];
            #pragma unroll
            for (int q = 0; q < 4; ++q) {
                xv[q * 4 + 0] = bf2f(raw[q].x);
                xv[q * 4 + 1] = bf2f(raw[q].y);
                xv[q * 4 + 2] = bf2f(raw[q].z);
                xv[q * 4 + 3] = bf2f(raw[q].w);
            }
            float s = 0.f, s2 = 0.f;
            #pragma unroll
            for (int e = 0; e < 16; ++e) { s += xv[e]; s2 += xv[e] * xv[e]; }
            s += __shfl_xor(s, 1);  s2 += __shfl_xor(s2, 1);
            s += __shfl_xor(s, 2);  s2 += __shfl_xor(s2, 2);
            float m = s * 0.015625f;
            float var = s2 * 0.015625f - m * m;
            float rstd = rsqrtf(var + 1e-5f);
            #pragma unroll
            for (int q = 0; q < 4; ++q) {
                float4 lg4 = ((const float4*)lno_g)[sub * 4 + q];
                float4 lb4 = ((const float4*)lno_b)[sub * 4 + q];
                ushort4 zw;
                zw.x = f2bf((xv[q * 4 + 0] - m) * rstd * lg4.x + lb4.x);
                zw.y = f2bf((xv[q * 4 + 1] - m) * rstd * lg4.y + lb4.y);
                zw.z = f2bf((xv[q * 4 + 2] - m) * rstd * lg4.z + lb4.z);
                zw.w = f2bf((xv[q * 4 + 3] - m) * rstd * lg4.w + lb4.w);
                *(ushort4*)&x2[row][sub * 16 + q * 4] = zw;
            }
        }
    }
    __syncthreads();

    unsigned short* o_lds = &x1[0][0];   // [128][64]
    const int rsel = lane & 15, koff = lane >> 4;
    #pragma unroll
    for (int mh = 0; mh < 2; ++mh) {
        const int mi = 2 * w + mh;
        bf16x8 a0 = *(const bf16x8*)&x2[mi * 16 + rsel][koff * 8];
        bf16x8 a1 = *(const bf16x8*)&x2[mi * 16 + rsel][32 + koff * 8];
        #pragma unroll
        for (int n = 0; n < 4; ++n) {
            f32x4 pacc = {0.f, 0.f, 0.f, 0.f};
            const unsigned short* wrow = WoutB + (size_t)(n * 16 + rsel) * 64;
            pacc = MFMA16(a0, *(const bf16x8*)&wrow[koff * 8], pacc);
            pacc = MFMA16(a1, *(const bf16x8*)&wrow[32 + koff * 8], pacc);
            const float bo = bout[n * 16 + rsel];
            #pragma unroll
            for (int r = 0; r < 4; ++r)
                o_lds[(mi * 16 + koff * 4 + r) * 64 + n * 16 + rsel] = f2bf(pacc[r] + bo);
        }
    }
    __syncthreads();

    #pragma unroll
    for (int q = 0; q < 4; ++q) {
        int e = q * 2048 + t * 8;
        int c = e >> 6, o = e & 63;
        size_t pos = (size_t)(bb * LL + irow) * LL + c0 + c;
        uint4 ov = *(const uint4*)&o_lds[c * 64 + o];
        uint4 gv = *(const uint4*)&G[pos * DD + o];
        const unsigned short* ovp = (const unsigned short*)&ov;
        const unsigned short* gvp = (const unsigned short*)&gv;
        float4 p0 = *(const float4*)&pairIn[pos * DD + o];
        float4 p1 = *(const float4*)&pairIn[pos * DD + o + 4];
        float4 r0, r1;
        r0.x = p0.x + bf2f(ovp[0]) * bf2f(gvp[0]);
        r0.y = p0.y + bf2f(ovp[1]) * bf2f(gvp[1]);
        r0.z = p0.z + bf2f(ovp[2]) * bf2f(gvp[2]);
        r0.w = p0.w + bf2f(ovp[3]) * bf2f(gvp[3]);
        r1.x = p1.x + bf2f(ovp[4]) * bf2f(gvp[4]);
        r1.y = p1.y + bf2f(ovp[5]) * bf2f(gvp[5]);
        r1.z = p1.z + bf2f(ovp[6]) * bf2f(gvp[6]);
        r1.w = p1.w + bf2f(ovp[7]) * bf2f(gvp[7]);
        *(float4*)&out[pos * DD + o] = r0;
        *(float4*)&out[pos * DD + o + 4] = r1;
    }
}

// ----------------------------------------------------------------- launch ---
extern "C" void kernel_launch(void* const* d_in, const int* in_sizes, int n_in,
                              void* d_out, int out_size, void* d_ws, size_t ws_size,
                              hipStream_t stream) {
    const float* pair    = (const float*)d_in[0];
    const float* torsion = (const float*)d_in[1];
    const float* ln_g    = (const float*)d_in[2];
    const float* ln_b    = (const float*)d_in[3];
    const float* Wl      = (const float*)d_in[4];
    const float* Wr      = (const float*)d_in[5];
    const float* Wlg     = (const float*)d_in[6];
    const float* blg     = (const float*)d_in[7];
    const float* Wrg     = (const float*)d_in[8];
    const float* brg     = (const float*)d_in[9];
    const float* Wog     = (const float*)d_in[10];
    const float* bog     = (const float*)d_in[11];
    const float* Wout    = (const float*)d_in[12];
    const float* bout    = (const float*)d_in[13];
    const float* lno_g   = (const float*)d_in[14];
    const float* lno_b   = (const float*)d_in[15];
    const float* Wt      = (const float*)d_in[16];
    const float* bt      = (const float*)d_in[17];
    float* outp = (float*)d_out;

    const size_t PLANE_B = (size_t)128 * LL * LL * 2;   // 64 MiB per block
    const size_t need = 4 * PLANE_B + (320 * 64 + 64 * 64) * 2;
    if (ws_size < need) return;

    char* ws = (char*)d_ws;
    unsigned short* At2   = (unsigned short*)(ws);
    unsigned short* Bt2   = (unsigned short*)(ws + PLANE_B);
    unsigned short* G     = (unsigned short*)(ws + 2 * PLANE_B);
    unsigned short* Xt    = (unsigned short*)(ws + 3 * PLANE_B);
    unsigned short* Wcat  = (unsigned short*)(ws + 4 * PLANE_B);
    unsigned short* WoutB = Wcat + 320 * 64;

    prep_w<<<dim3(40), dim3(256), 0, stream>>>(Wl, Wr, Wlg, Wrg, Wog, Wout, Wcat, WoutB);
    k1_proj<<<dim3(16, 128, 2), dim3(256), 0, stream>>>(pair, torsion, ln_g, ln_b, blg, brg,
                                                        bog, Wt, bt, Wcat, At2, Bt2, G);
    k2_gemm<<<dim3(16, 128), dim3(256), 0, stream>>>(At2, Bt2, Xt);
    k3_out<<<dim3(4, LL, 2), dim3(256), 0, stream>>>(Xt, G, pair, WoutB, lno_g, lno_b, bout, outp);
}